// Round 3
// baseline (713.910 us; speedup 1.0000x reference)
//
#include <hip/hip_runtime.h>

#define HD 64
#define BN_EPS 1e-5f

__device__ __forceinline__ unsigned tobf(float x) {
    unsigned u = __float_as_uint(x);
    return (u + 0x7fffu + ((u >> 16) & 1u)) >> 16;
}

// ---------- CSR construction ----------

__global__ void k_deg(const int* __restrict__ dst, int* __restrict__ deg, int E) {
    int e = blockIdx.x * blockDim.x + threadIdx.x;
    if (e < E) atomicAdd(&deg[dst[e]], 1);
}

__global__ void k_dinv(const int* __restrict__ deg, float* __restrict__ dinv, int N) {
    int i = blockIdx.x * blockDim.x + threadIdx.x;
    if (i < N) dinv[i] = rsqrtf((float)(deg[i] + 1));  // +1 self-loop
}

__global__ void k_scan1(const int* __restrict__ deg, int* __restrict__ incl,
                        int* __restrict__ bsums, int N) {
    __shared__ int s[256];
    int tid = threadIdx.x;
    int i = blockIdx.x * 256 + tid;
    int v = (i < N) ? deg[i] : 0;
    s[tid] = v;
    __syncthreads();
    for (int off = 1; off < 256; off <<= 1) {
        int t = (tid >= off) ? s[tid - off] : 0;
        __syncthreads();
        s[tid] += t;
        __syncthreads();
    }
    if (i < N) incl[i] = s[tid];
    if (tid == 255) bsums[blockIdx.x] = s[255];
}

__global__ void k_scan2(int* bsums, int nb) {
    __shared__ int s[512];
    int tid = threadIdx.x;
    int own = (tid < nb) ? bsums[tid] : 0;
    s[tid] = own;
    __syncthreads();
    for (int off = 1; off < 512; off <<= 1) {
        int t = (tid >= off) ? s[tid - off] : 0;
        __syncthreads();
        s[tid] += t;
        __syncthreads();
    }
    if (tid < nb) bsums[tid] = s[tid] - own;  // exclusive
}

__global__ void k_scan3(int* __restrict__ rowp, const int* __restrict__ deg,
                        const int* __restrict__ bsums, int N, int E) {
    int i = blockIdx.x * 256 + threadIdx.x;
    if (i < N) rowp[i] = rowp[i] - deg[i] + bsums[blockIdx.x];  // global exclusive
    if (i == 0) rowp[N] = E;
}

// bucket edges into CSR slots; payload = src index only (norm folded into rows)
__global__ void k_fill(const int* __restrict__ src, const int* __restrict__ dst,
                       const int* __restrict__ rowp, int* __restrict__ cur,
                       int* __restrict__ ed, int E) {
    int e = blockIdx.x * blockDim.x + threadIdx.x;
    if (e >= E) return;
    int d = dst[e];
    int pos = rowp[d] + atomicAdd(&cur[d], 1);
    ed[pos] = src[e];
}

// per-graph node counts via binary search on sorted batch
__global__ void k_gcnt(const int* __restrict__ batch, int* __restrict__ cnt, int N, int G) {
    int g = blockIdx.x * blockDim.x + threadIdx.x;
    if (g >= G) return;
    int lo = 0, hi = N;
    while (lo < hi) { int mid = (lo + hi) >> 1; if (batch[mid] < g) lo = mid + 1; else hi = mid; }
    int lo2 = lo, hi2 = N;
    while (lo2 < hi2) { int mid = (lo2 + hi2) >> 1; if (batch[mid] < g + 1) lo2 = mid + 1; else hi2 = mid; }
    cnt[g] = lo2 - lo;
}

// ---------- per-layer kernels ----------

// hWs[i][f] = bf16( dinv[i] * (sum_k A[i][k]*W[f][k] + cb[f]) ), W in regs, lane=f
template<int ABF>
__global__ __launch_bounds__(256) void k_gemm(const void* __restrict__ Aptr,
                                              const float* __restrict__ W,
                                              const float* __restrict__ cb,
                                              const float* __restrict__ dinv,
                                              unsigned short* __restrict__ hWs, int N) {
    int lane = threadIdx.x & 63;
    float w[64];
    const float4* Wv = (const float4*)(W + lane * HD);
#pragma unroll
    for (int kk = 0; kk < 16; kk++) {
        float4 t = Wv[kk];
        w[4 * kk] = t.x; w[4 * kk + 1] = t.y; w[4 * kk + 2] = t.z; w[4 * kk + 3] = t.w;
    }
    float cv = cb ? cb[lane] : 0.f;
    int wid = (blockIdx.x * blockDim.x + threadIdx.x) >> 6;
    int nw = (gridDim.x * blockDim.x) >> 6;
    for (int i = wid; i < N; i += nw) {
        float a0 = cv, a1 = 0.f, a2 = 0.f, a3 = 0.f;
        if (ABF) {
            const uint2* Av = (const uint2*)((const unsigned short*)Aptr + (size_t)i * HD);
#pragma unroll
            for (int q = 0; q < 16; q++) {
                uint2 u = Av[q];  // 4 bf16 feats, wave-uniform
                float f0 = __uint_as_float(u.x << 16);
                float f1 = __uint_as_float(u.x & 0xffff0000u);
                float f2 = __uint_as_float(u.y << 16);
                float f3 = __uint_as_float(u.y & 0xffff0000u);
                a0 = fmaf(f0, w[4 * q], a0);
                a1 = fmaf(f1, w[4 * q + 1], a1);
                a2 = fmaf(f2, w[4 * q + 2], a2);
                a3 = fmaf(f3, w[4 * q + 3], a3);
            }
        } else {
            const float4* Av = (const float4*)((const float*)Aptr + (size_t)i * HD);
#pragma unroll
            for (int kk = 0; kk < 16; kk++) {
                float4 hv = Av[kk];
                a0 = fmaf(hv.x, w[4 * kk], a0);
                a1 = fmaf(hv.y, w[4 * kk + 1], a1);
                a2 = fmaf(hv.z, w[4 * kk + 2], a2);
                a3 = fmaf(hv.w, w[4 * kk + 3], a3);
            }
        }
        float v = (a0 + a1) + (a2 + a3);
        hWs[(size_t)i * HD + lane] = (unsigned short)tobf(v * dinv[i]);
    }
}

// one wave per contiguous node chunk; lanes 0-31 handle even edges, 32-63 odd.
// Each lane loads a uint (2 bf16 feats) of its edge's row: 1 cache line per edge.
__global__ __launch_bounds__(256) void k_agg(const int* __restrict__ rowp,
                                             const int* __restrict__ ed,
                                             const float* __restrict__ dinv,
                                             const unsigned* __restrict__ hWs,
                                             const float* __restrict__ bias,
                                             const int* __restrict__ batch,
                                             void* __restrict__ outp, int outBf,
                                             float* __restrict__ stats,
                                             float* __restrict__ praw,
                                             int N, int chunk, int E) {
    int tid = threadIdx.x;
    int lane = tid & 63;
    int half = lane >> 5;
    int m = lane & 31;
    int wid = blockIdx.x * 4 + (tid >> 6);
    int i0 = wid * chunk, i1 = min(i0 + chunk, N);
    float b0 = bias[2 * m], b1 = bias[2 * m + 1];
    float bs0 = 0.f, bs1 = 0.f, bq0 = 0.f, bq1 = 0.f;
    int curb = -1;
    float p0 = 0.f, p1 = 0.f;
    for (int i = i0; i < i1; i++) {
        int rs = rowp[i], re = rowp[i + 1];
        int cnt = re - rs + 1;  // + self message
        int npair = (cnt + 1) >> 1;
        float acc0 = 0.f, acc1 = 0.f;
#pragma unroll 4
        for (int j = 0; j < npair; j++) {
            int t = 2 * j + half;           // virtual msg idx: 0=self, k>0 -> ed[rs+k-1]
            int e = rs + t - 1;
            e = max(e, rs); e = min(e, E - 1);
            int s = ed[e];
            s = (t == 0) ? i : s;
            unsigned u = hWs[(size_t)s * 32 + m];
            bool v = (t < cnt);
            float f0 = __uint_as_float(u << 16);
            float f1 = __uint_as_float(u & 0xffff0000u);
            acc0 += v ? f0 : 0.f;
            acc1 += v ? f1 : 0.f;
        }
        acc0 += __shfl_xor(acc0, 32);
        acc1 += __shfl_xor(acc1, 32);
        float di = dinv[i];
        float h0 = fmaxf(fmaf(di, acc0, b0), 0.f);
        float h1 = fmaxf(fmaf(di, acc1, b1), 0.f);
        int b = batch[i];
        if (lane < 32) {
            if (outBf) ((unsigned*)outp)[(size_t)i * 32 + m] = tobf(h0) | (tobf(h1) << 16);
            else ((float2*)outp)[(size_t)i * 32 + m] = make_float2(h0, h1);
            bs0 += h0; bs1 += h1;
            bq0 = fmaf(h0, h0, bq0); bq1 = fmaf(h1, h1, bq1);
            if (b != curb) {
                if (curb >= 0) {
                    atomicAdd(&praw[(size_t)curb * HD + 2 * m], p0);
                    atomicAdd(&praw[(size_t)curb * HD + 2 * m + 1], p1);
                }
                curb = b; p0 = h0; p1 = h1;
            } else { p0 += h0; p1 += h1; }
        }
    }
    if (lane < 32 && curb >= 0) {
        atomicAdd(&praw[(size_t)curb * HD + 2 * m], p0);
        atomicAdd(&praw[(size_t)curb * HD + 2 * m + 1], p1);
    }
    __shared__ float r1[4][HD], r2[4][HD];
    int wv = tid >> 6;
    if (lane < 32) {
        r1[wv][2 * m] = bs0; r1[wv][2 * m + 1] = bs1;
        r2[wv][2 * m] = bq0; r2[wv][2 * m + 1] = bq1;
    }
    __syncthreads();
    if (tid < HD) {
        float a = r1[0][tid] + r1[1][tid] + r1[2][tid] + r1[3][tid];
        float c = r2[0][tid] + r2[1][tid] + r2[2][tid] + r2[3][tid];
        atomicAdd(&stats[tid], a);
        atomicAdd(&stats[HD + tid], c);
    }
}

// BN finalize + fold affine into next layer's weights (one dispatch)
__global__ void k_bnfold(const float* __restrict__ stats, const float* __restrict__ g,
                         const float* __restrict__ beta, float* __restrict__ ss,
                         const float* __restrict__ Wnext, float* __restrict__ Wf,
                         float* __restrict__ cf, float invN) {
    __shared__ float lss[128];
    int f = threadIdx.x;  // 64
    float mean = stats[f] * invN;
    float var = stats[64 + f] * invN - mean * mean;
    float inv = rsqrtf(var + BN_EPS);
    float sc = g[f] * inv;
    float sh = beta[f] - mean * sc;
    ss[f] = sc; ss[64 + f] = sh;
    lss[f] = sc; lss[64 + f] = sh;
    __syncthreads();
    if (Wnext) {
        float c = 0.f;
        for (int k = 0; k < HD; k++) {
            float w = Wnext[f * HD + k];
            Wf[f * HD + k] = w * lss[k];
            c = fmaf(lss[64 + k], w, c);
        }
        cf[f] = c;
    }
}

// fused: normalize final h in place (float4) + pool finalize
__global__ __launch_bounds__(256) void k_fin(float* __restrict__ h,
                                             const float* __restrict__ ss_all,
                                             const float* __restrict__ praw,
                                             const int* __restrict__ cnt,
                                             float* __restrict__ pool,
                                             int nquads, int G) {
    int nb1 = (nquads + 255) >> 8;
    if ((int)blockIdx.x < nb1) {
        int idx = blockIdx.x * 256 + threadIdx.x;
        if (idx >= nquads) return;
        const float* ss = ss_all + 2 * 128;
        float4* h4 = (float4*)h;
        float4 v = h4[idx];
        int f0 = (idx * 4) & 63;
        v.x = fmaf(v.x, ss[f0 + 0], ss[64 + f0 + 0]);
        v.y = fmaf(v.y, ss[f0 + 1], ss[64 + f0 + 1]);
        v.z = fmaf(v.z, ss[f0 + 2], ss[64 + f0 + 2]);
        v.w = fmaf(v.w, ss[f0 + 3], ss[64 + f0 + 3]);
        h4[idx] = v;
    } else {
        int idx = (blockIdx.x - nb1) * 256 + threadIdx.x;
        if (idx >= G * 192) return;
        int g = idx / 192;
        int r = idx - g * 192;
        int l = r >> 6;
        int f = r & 63;
        const float* ss = ss_all + l * 128;
        float v = praw[((size_t)l * G + g) * HD + f];
        pool[idx] = fmaf(ss[f], v, (float)cnt[g] * ss[64 + f]);
    }
}

extern "C" void kernel_launch(void* const* d_in, const int* in_sizes, int n_in,
                              void* d_out, int out_size, void* d_ws, size_t ws_size,
                              hipStream_t stream) {
    const int N = in_sizes[0] / HD;             // 100000
    const int E = in_sizes[1] / 2;              // 1000000
    const int G = (out_size - N * HD) / 192;    // 512

    const float* x = (const float*)d_in[0];
    const int* ei = (const int*)d_in[1];
    const int* srcA = ei;
    const int* dstA = ei + E;
    const int* batch = (const int*)d_in[2];
    const float* W[3]    = {(const float*)d_in[3], (const float*)d_in[7],  (const float*)d_in[11]};
    const float* bias[3] = {(const float*)d_in[4], (const float*)d_in[8],  (const float*)d_in[12]};
    const float* gam[3]  = {(const float*)d_in[5], (const float*)d_in[9],  (const float*)d_in[13]};
    const float* bet[3]  = {(const float*)d_in[6], (const float*)d_in[10], (const float*)d_in[14]};

    char* ws = (char*)d_ws;
    size_t off = 0;
    auto alloc = [&](size_t bytes) -> void* {
        void* p = ws + off;
        off = (off + bytes + 255) & ~(size_t)255;
        return p;
    };
    // zero-region (one memset): deg, cur, stats, praw
    int* deg     = (int*)alloc((size_t)N * 4);
    int* cur     = (int*)alloc((size_t)N * 4);
    float* stats = (float*)alloc(3 * 128 * 4);
    float* praw  = (float*)alloc((size_t)3 * G * HD * 4);
    size_t zbytes = off;  // from start of deg (offset 0)
    float* dinv  = (float*)alloc((size_t)N * 4);
    int* rowp    = (int*)alloc((size_t)(N + 1) * 4);
    int* bsums   = (int*)alloc(512 * 4);
    int* ed      = (int*)alloc((size_t)E * 4 + 256);
    unsigned short* hWs  = (unsigned short*)alloc((size_t)N * HD * 2);
    unsigned short* hraw = (unsigned short*)alloc((size_t)N * HD * 2);
    float* ss    = (float*)alloc(3 * 128 * 4);
    float* Wf    = (float*)alloc(2 * HD * HD * 4);
    float* cf    = (float*)alloc(2 * HD * 4);
    int* gcnt    = (int*)alloc((size_t)G * 4);
    (void)ws_size;

    float* pool = (float*)d_out;                      // [G,192]
    float* hbuf = (float*)d_out + (size_t)G * 192;    // [N,64] final h (fp32)

    hipMemsetAsync(deg, 0, zbytes, stream);

    int nb = (N + 255) / 256;
    k_deg<<<(E + 255) / 256, 256, 0, stream>>>(dstA, deg, E);
    k_dinv<<<nb, 256, 0, stream>>>(deg, dinv, N);
    k_scan1<<<nb, 256, 0, stream>>>(deg, rowp, bsums, N);
    k_scan2<<<1, 512, 0, stream>>>(bsums, nb);
    k_scan3<<<nb, 256, 0, stream>>>(rowp, deg, bsums, N, E);
    k_fill<<<(E + 255) / 256, 256, 0, stream>>>(srcA, dstA, rowp, cur, ed, E);
    k_gcnt<<<(G + 255) / 256, 256, 0, stream>>>(batch, gcnt, N, G);

    const int AGG_BLOCKS = 2048;
    const int NW = AGG_BLOCKS * 4;
    const int chunk = (N + NW - 1) / NW;

    for (int l = 0; l < 3; l++) {
        const float* Wl = (l == 0) ? W[0] : (Wf + (l - 1) * HD * HD);
        const float* cl = (l == 0) ? nullptr : (cf + (l - 1) * HD);
        if (l == 0)
            k_gemm<0><<<1024, 256, 0, stream>>>(x, Wl, cl, dinv, hWs, N);
        else
            k_gemm<1><<<1024, 256, 0, stream>>>(hraw, Wl, cl, dinv, hWs, N);
        void* outp = (l < 2) ? (void*)hraw : (void*)hbuf;
        k_agg<<<AGG_BLOCKS, 256, 0, stream>>>(rowp, ed, dinv, (const unsigned*)hWs,
                                              bias[l], batch, outp, (l < 2) ? 1 : 0,
                                              stats + l * 128, praw + (size_t)l * G * HD,
                                              N, chunk, E);
        k_bnfold<<<1, 64, 0, stream>>>(stats + l * 128, gam[l], bet[l], ss + l * 128,
                                       (l < 2) ? W[l + 1] : nullptr,
                                       Wf + (l < 2 ? l : 0) * HD * HD,
                                       cf + (l < 2 ? l : 0) * HD, 1.0f / (float)N);
    }
    int nquads = N * HD / 4;
    int nb1 = (nquads + 255) / 256;
    int nb2 = (G * 192 + 255) / 256;
    k_fin<<<nb1 + nb2, 256, 0, stream>>>(hbuf, ss, praw, gcnt, pool, nquads, G);
}

// Round 4
// 549.157 us; speedup vs baseline: 1.3000x; 1.3000x over previous
//
#include <hip/hip_runtime.h>

#define HD 64
#define BN_EPS 1e-5f

typedef __attribute__((ext_vector_type(8))) short bfrag;
typedef __attribute__((ext_vector_type(4))) float ffrag;

__device__ __forceinline__ unsigned tobf(float x) {
    unsigned u = __float_as_uint(x);
    return (u + 0x7fffu + ((u >> 16) & 1u)) >> 16;
}
__device__ __forceinline__ float bf_lo(unsigned u) { return __uint_as_float(u << 16); }
__device__ __forceinline__ float bf_hi(unsigned u) { return __uint_as_float(u & 0xffff0000u); }

// ---------- CSR construction ----------

__global__ void k_deg(const int* __restrict__ dst, int* __restrict__ deg, int E) {
    int e = blockIdx.x * blockDim.x + threadIdx.x;
    if (e < E) atomicAdd(&deg[dst[e]], 1);
}

// scan of deg (256/block) + dinv fused
__global__ void k_scan1(const int* __restrict__ deg, int* __restrict__ incl,
                        int* __restrict__ bsums, float* __restrict__ dinv, int N) {
    __shared__ int s[256];
    int tid = threadIdx.x;
    int i = blockIdx.x * 256 + tid;
    int v = (i < N) ? deg[i] : 0;
    s[tid] = v;
    __syncthreads();
    for (int off = 1; off < 256; off <<= 1) {
        int t = (tid >= off) ? s[tid - off] : 0;
        __syncthreads();
        s[tid] += t;
        __syncthreads();
    }
    if (i < N) {
        incl[i] = s[tid];
        dinv[i] = rsqrtf((float)(v + 1));  // +1 self-loop
    }
    if (tid == 255) bsums[blockIdx.x] = s[255];
}

__global__ void k_scan2(int* bsums, int nb) {
    __shared__ int s[512];
    int tid = threadIdx.x;
    int own = (tid < nb) ? bsums[tid] : 0;
    s[tid] = own;
    __syncthreads();
    for (int off = 1; off < 512; off <<= 1) {
        int t = (tid >= off) ? s[tid - off] : 0;
        __syncthreads();
        s[tid] += t;
        __syncthreads();
    }
    if (tid < nb) bsums[tid] = s[tid] - own;  // exclusive
}

__global__ void k_scan3(int* __restrict__ rowp, const int* __restrict__ deg,
                        const int* __restrict__ bsums, int N, int E) {
    int i = blockIdx.x * 256 + threadIdx.x;
    if (i < N) rowp[i] = rowp[i] - deg[i] + bsums[blockIdx.x];
    if (i == 0) rowp[N] = E;
}

// bucket edges into CSR slots (payload = src only) + per-graph counts fused
__global__ void k_fill(const int* __restrict__ src, const int* __restrict__ dst,
                       const int* __restrict__ rowp, int* __restrict__ cur,
                       int* __restrict__ ed, const int* __restrict__ batch,
                       int* __restrict__ cnt, int E, int N, int G) {
    int e = blockIdx.x * blockDim.x + threadIdx.x;
    if (e < G) {
        int g = e;
        int lo = 0, hi = N;
        while (lo < hi) { int mid = (lo + hi) >> 1; if (batch[mid] < g) lo = mid + 1; else hi = mid; }
        int lo2 = lo, hi2 = N;
        while (lo2 < hi2) { int mid = (lo2 + hi2) >> 1; if (batch[mid] < g + 1) lo2 = mid + 1; else hi2 = mid; }
        cnt[g] = lo2 - lo;
    }
    if (e >= E) return;
    int d = dst[e];
    int pos = rowp[d] + atomicAdd(&cur[d], 1);
    ed[pos] = src[e];
}

// ---------- MFMA gemm: hWs[i][f] = bf16( dinv[i]*(sum_k A[i][k]*W[f][k] + cb[f]) ) ----------
template<int FP32IN>
__global__ __launch_bounds__(256) void k_gemm2(const void* __restrict__ Aptr,
                                               const void* __restrict__ Wptr,
                                               const float* __restrict__ cb,
                                               const float* __restrict__ dinv,
                                               unsigned short* __restrict__ hWs,
                                               int N, int ntiles) {
    int lane = threadIdx.x & 63;
    int m = lane & 15, quad = lane >> 4;
    // B-operand frags: lane holds W[n=ft*16+m][k=kf*32+quad*8+j], 16B contiguous
    bfrag wf[4][2];
    if (FP32IN) {
        const float* W = (const float*)Wptr;
#pragma unroll
        for (int ft = 0; ft < 4; ft++)
#pragma unroll
            for (int kf = 0; kf < 2; kf++) {
                const float4* p4 = (const float4*)(W + (ft * 16 + m) * HD + kf * 32 + quad * 8);
                float4 x0 = p4[0], x1 = p4[1];
                union { unsigned u[4]; bfrag b; } r;
                r.u[0] = tobf(x0.x) | (tobf(x0.y) << 16);
                r.u[1] = tobf(x0.z) | (tobf(x0.w) << 16);
                r.u[2] = tobf(x1.x) | (tobf(x1.y) << 16);
                r.u[3] = tobf(x1.z) | (tobf(x1.w) << 16);
                wf[ft][kf] = r.b;
            }
    } else {
        const unsigned short* W = (const unsigned short*)Wptr;
#pragma unroll
        for (int ft = 0; ft < 4; ft++)
#pragma unroll
            for (int kf = 0; kf < 2; kf++)
                wf[ft][kf] = *(const bfrag*)(W + (ft * 16 + m) * HD + kf * 32 + quad * 8);
    }
    float cbv[4];
#pragma unroll
    for (int ft = 0; ft < 4; ft++) cbv[ft] = cb ? cb[ft * 16 + m] : 0.f;

    int wid = (blockIdx.x * blockDim.x + threadIdx.x) >> 6;
    int nw = (gridDim.x * blockDim.x) >> 6;
    for (int tile = wid; tile < ntiles; tile += nw) {
        int arow = min(tile * 16 + m, N - 1);
        bfrag a0, a1;
        if (FP32IN) {
            const float4* p4 = (const float4*)((const float*)Aptr + (size_t)arow * HD + quad * 8);
            float4 x0 = p4[0], x1 = p4[1], y0 = p4[8], y1 = p4[9];
            union { unsigned u[4]; bfrag b; } r0, r1;
            r0.u[0] = tobf(x0.x) | (tobf(x0.y) << 16);
            r0.u[1] = tobf(x0.z) | (tobf(x0.w) << 16);
            r0.u[2] = tobf(x1.x) | (tobf(x1.y) << 16);
            r0.u[3] = tobf(x1.z) | (tobf(x1.w) << 16);
            r1.u[0] = tobf(y0.x) | (tobf(y0.y) << 16);
            r1.u[1] = tobf(y0.z) | (tobf(y0.w) << 16);
            r1.u[2] = tobf(y1.x) | (tobf(y1.y) << 16);
            r1.u[3] = tobf(y1.z) | (tobf(y1.w) << 16);
            a0 = r0.b; a1 = r1.b;
        } else {
            const unsigned short* p = (const unsigned short*)Aptr + (size_t)arow * HD + quad * 8;
            a0 = *(const bfrag*)p;
            a1 = *(const bfrag*)(p + 32);
        }
        ffrag acc[4];
#pragma unroll
        for (int ft = 0; ft < 4; ft++) {
            acc[ft] = (ffrag){0.f, 0.f, 0.f, 0.f};
            acc[ft] = __builtin_amdgcn_mfma_f32_16x16x32_bf16(a0, wf[ft][0], acc[ft], 0, 0, 0);
            acc[ft] = __builtin_amdgcn_mfma_f32_16x16x32_bf16(a1, wf[ft][1], acc[ft], 0, 0, 0);
        }
        // C/D: node = tile*16 + quad*4 + r, feat = ft*16 + m
        int r0n = tile * 16 + quad * 4;
        float dv[4];
#pragma unroll
        for (int r = 0; r < 4; r++) dv[r] = dinv[min(r0n + r, N - 1)];
#pragma unroll
        for (int ft = 0; ft < 4; ft++)
#pragma unroll
            for (int r = 0; r < 4; r++) {
                int nrow = r0n + r;
                if (nrow < N) {
                    float v = (acc[ft][r] + cbv[ft]) * dv[r];
                    hWs[(size_t)nrow * HD + ft * 16 + m] = (unsigned short)tobf(v);
                }
            }
    }
}

// ---------- aggregation: wave per node chunk, lane-parallel ed stage + shfl,
// 8-deep gathers per half (16 messages per block), bf16 rows = 1 line/edge ----------
__global__ __launch_bounds__(256) void k_agg(const int* __restrict__ rowp,
                                             const int* __restrict__ ed,
                                             const float* __restrict__ dinv,
                                             const unsigned* __restrict__ hWs,
                                             const float* __restrict__ bias,
                                             const int* __restrict__ batch,
                                             void* __restrict__ outp, int outBf,
                                             float* __restrict__ stats,
                                             float* __restrict__ praw,
                                             int N, int chunk) {
    int tid = threadIdx.x;
    int lane = tid & 63;
    int hf = lane >> 5;
    int m = lane & 31;
    int wid = blockIdx.x * 4 + (tid >> 6);
    int i0 = wid * chunk, i1 = min(i0 + chunk, N);
    float b0 = bias[2 * m], b1 = bias[2 * m + 1];
    float bs0 = 0.f, bs1 = 0.f, bq0 = 0.f, bq1 = 0.f;
    int curb = -1;
    float p0 = 0.f, p1 = 0.f;
    for (int i = i0; i < i1; i++) {
        int rs = rowp[i], re = rowp[i + 1];
        unsigned us = (hf == 0) ? hWs[(size_t)i * 32 + m] : 0u;  // self row (half 0 only)
        float acc0 = bf_lo(us), acc1 = bf_hi(us);
        for (int base = rs; base < re; base += 64) {
            int avail = min(64, re - base);
            int eidx = ed[base + lane];  // padded tail; garbage lanes never selected
            int nblk = (avail + 15) >> 4;
            for (int blk = 0; blk < nblk; blk++) {
                int t0 = (blk << 4) + hf;
                unsigned u[8];
                float v0[8], v1[8];
#pragma unroll
                for (int jj = 0; jj < 8; jj++) {
                    int t = t0 + 2 * jj;
                    int tc = min(t, avail - 1);
                    int s = __shfl(eidx, tc);
                    u[jj] = hWs[(size_t)s * 32 + m];
                    bool val = t < avail;
                    v0[jj] = val ? 1.f : 0.f;
                    v1[jj] = val ? 1.f : 0.f;
                }
#pragma unroll
                for (int jj = 0; jj < 8; jj++) {
                    acc0 = fmaf(v0[jj], bf_lo(u[jj]), acc0);
                    acc1 = fmaf(v1[jj], bf_hi(u[jj]), acc1);
                }
            }
        }
        acc0 += __shfl_xor(acc0, 32);
        acc1 += __shfl_xor(acc1, 32);
        float di = dinv[i];
        float h0 = fmaxf(fmaf(di, acc0, b0), 0.f);
        float h1 = fmaxf(fmaf(di, acc1, b1), 0.f);
        int b = batch[i];
        if (lane < 32) {
            if (outBf) ((unsigned*)outp)[(size_t)i * 32 + m] = tobf(h0) | (tobf(h1) << 16);
            else ((float2*)outp)[(size_t)i * 32 + m] = make_float2(h0, h1);
            bs0 += h0; bs1 += h1;
            bq0 = fmaf(h0, h0, bq0); bq1 = fmaf(h1, h1, bq1);
            if (b != curb) {
                if (curb >= 0) {
                    atomicAdd(&praw[(size_t)curb * HD + 2 * m], p0);
                    atomicAdd(&praw[(size_t)curb * HD + 2 * m + 1], p1);
                }
                curb = b; p0 = h0; p1 = h1;
            } else { p0 += h0; p1 += h1; }
        }
    }
    if (lane < 32 && curb >= 0) {
        atomicAdd(&praw[(size_t)curb * HD + 2 * m], p0);
        atomicAdd(&praw[(size_t)curb * HD + 2 * m + 1], p1);
    }
    __shared__ float r1s[4][HD], r2s[4][HD];
    int wv = tid >> 6;
    if (lane < 32) {
        r1s[wv][2 * m] = bs0; r1s[wv][2 * m + 1] = bs1;
        r2s[wv][2 * m] = bq0; r2s[wv][2 * m + 1] = bq1;
    }
    __syncthreads();
    if (tid < HD) {
        float a = r1s[0][tid] + r1s[1][tid] + r1s[2][tid] + r1s[3][tid];
        float c = r2s[0][tid] + r2s[1][tid] + r2s[2][tid] + r2s[3][tid];
        atomicAdd(&stats[tid], a);
        atomicAdd(&stats[HD + tid], c);
    }
}

// BN finalize + fold affine into next layer's weights (bf16) in one dispatch
__global__ void k_bnfold(const float* __restrict__ stats, const float* __restrict__ g,
                         const float* __restrict__ beta, float* __restrict__ ss,
                         const float* __restrict__ Wnext, unsigned* __restrict__ Wfb,
                         float* __restrict__ cf, float invN) {
    __shared__ float lss[128];
    int f = threadIdx.x;  // 64
    float mean = stats[f] * invN;
    float var = stats[64 + f] * invN - mean * mean;
    float inv = rsqrtf(var + BN_EPS);
    float sc = g[f] * inv;
    float sh = beta[f] - mean * sc;
    ss[f] = sc; ss[64 + f] = sh;
    lss[f] = sc; lss[64 + f] = sh;
    __syncthreads();
    if (Wnext) {
        float c = 0.f;
        for (int q = 0; q < 32; q++) {
            float wa = Wnext[f * HD + 2 * q];
            float wb = Wnext[f * HD + 2 * q + 1];
            Wfb[f * 32 + q] = tobf(wa * lss[2 * q]) | (tobf(wb * lss[2 * q + 1]) << 16);
            c = fmaf(lss[64 + 2 * q], wa, c);
            c = fmaf(lss[64 + 2 * q + 1], wb, c);
        }
        cf[f] = c;
    }
}

// fused: normalize final h in place (float4) + pool finalize
__global__ __launch_bounds__(256) void k_fin(float* __restrict__ h,
                                             const float* __restrict__ ss_all,
                                             const float* __restrict__ praw,
                                             const int* __restrict__ cnt,
                                             float* __restrict__ pool,
                                             int nquads, int G) {
    int nb1 = (nquads + 255) >> 8;
    if ((int)blockIdx.x < nb1) {
        int idx = blockIdx.x * 256 + threadIdx.x;
        if (idx >= nquads) return;
        const float* ss = ss_all + 2 * 128;
        float4* h4 = (float4*)h;
        float4 v = h4[idx];
        int f0 = (idx * 4) & 63;
        v.x = fmaf(v.x, ss[f0 + 0], ss[64 + f0 + 0]);
        v.y = fmaf(v.y, ss[f0 + 1], ss[64 + f0 + 1]);
        v.z = fmaf(v.z, ss[f0 + 2], ss[64 + f0 + 2]);
        v.w = fmaf(v.w, ss[f0 + 3], ss[64 + f0 + 3]);
        h4[idx] = v;
    } else {
        int idx = (blockIdx.x - nb1) * 256 + threadIdx.x;
        if (idx >= G * 192) return;
        int g = idx / 192;
        int r = idx - g * 192;
        int l = r >> 6;
        int f = r & 63;
        const float* ss = ss_all + l * 128;
        float v = praw[((size_t)l * G + g) * HD + f];
        pool[idx] = fmaf(ss[f], v, (float)cnt[g] * ss[64 + f]);
    }
}

extern "C" void kernel_launch(void* const* d_in, const int* in_sizes, int n_in,
                              void* d_out, int out_size, void* d_ws, size_t ws_size,
                              hipStream_t stream) {
    const int N = in_sizes[0] / HD;             // 100000
    const int E = in_sizes[1] / 2;              // 1000000
    const int G = (out_size - N * HD) / 192;    // 512

    const float* x = (const float*)d_in[0];
    const int* ei = (const int*)d_in[1];
    const int* srcA = ei;
    const int* dstA = ei + E;
    const int* batch = (const int*)d_in[2];
    const float* W[3]    = {(const float*)d_in[3], (const float*)d_in[7],  (const float*)d_in[11]};
    const float* bias[3] = {(const float*)d_in[4], (const float*)d_in[8],  (const float*)d_in[12]};
    const float* gam[3]  = {(const float*)d_in[5], (const float*)d_in[9],  (const float*)d_in[13]};
    const float* bet[3]  = {(const float*)d_in[6], (const float*)d_in[10], (const float*)d_in[14]};

    char* ws = (char*)d_ws;
    size_t off = 0;
    auto alloc = [&](size_t bytes) -> void* {
        void* p = ws + off;
        off = (off + bytes + 255) & ~(size_t)255;
        return p;
    };
    // zero-region (single memset): deg, cur, stats, praw
    int* deg     = (int*)alloc((size_t)N * 4);
    int* cur     = (int*)alloc((size_t)N * 4);
    float* stats = (float*)alloc(3 * 128 * 4);
    float* praw  = (float*)alloc((size_t)3 * G * HD * 4);
    size_t zbytes = off;
    float* dinv  = (float*)alloc((size_t)N * 4);
    int* rowp    = (int*)alloc((size_t)(N + 1) * 4);
    int* bsums   = (int*)alloc(512 * 4);
    int* ed      = (int*)alloc((size_t)E * 4 + 256);
    unsigned short* hWs  = (unsigned short*)alloc((size_t)N * HD * 2);
    unsigned short* hraw = (unsigned short*)alloc((size_t)N * HD * 2);
    float* ss    = (float*)alloc(3 * 128 * 4);
    unsigned* Wfb = (unsigned*)alloc(2 * HD * 32 * 4);
    float* cf    = (float*)alloc(2 * HD * 4);
    int* gcnt    = (int*)alloc((size_t)G * 4);
    (void)ws_size;

    float* pool = (float*)d_out;                      // [G,192]
    float* hbuf = (float*)d_out + (size_t)G * 192;    // [N,64] final h (fp32)

    hipMemsetAsync(deg, 0, zbytes, stream);

    int nb = (N + 255) / 256;
    k_deg<<<(E + 255) / 256, 256, 0, stream>>>(dstA, deg, E);
    k_scan1<<<nb, 256, 0, stream>>>(deg, rowp, bsums, dinv, N);
    k_scan2<<<1, 512, 0, stream>>>(bsums, nb);
    k_scan3<<<nb, 256, 0, stream>>>(rowp, deg, bsums, N, E);
    k_fill<<<(E + 255) / 256, 256, 0, stream>>>(srcA, dstA, rowp, cur, ed, batch, gcnt, E, N, G);

    const int AGG_BLOCKS = 2048;
    const int NW = AGG_BLOCKS * 4;
    const int chunk = (N + NW - 1) / NW;
    const int ntiles = (N + 15) / 16;

    for (int l = 0; l < 3; l++) {
        if (l == 0)
            k_gemm2<1><<<640, 256, 0, stream>>>(x, W[0], nullptr, dinv, hWs, N, ntiles);
        else
            k_gemm2<0><<<640, 256, 0, stream>>>(hraw, Wfb + (size_t)(l - 1) * HD * 32,
                                                cf + (l - 1) * HD, dinv, hWs, N, ntiles);
        void* outp = (l < 2) ? (void*)hraw : (void*)hbuf;
        k_agg<<<AGG_BLOCKS, 256, 0, stream>>>(rowp, ed, dinv, (const unsigned*)hWs,
                                              bias[l], batch, outp, (l < 2) ? 1 : 0,
                                              stats + l * 128, praw + (size_t)l * G * HD,
                                              N, chunk);
        k_bnfold<<<1, 64, 0, stream>>>(stats + l * 128, gam[l], bet[l], ss + l * 128,
                                       (l < 2) ? W[l + 1] : nullptr,
                                       Wfb + (size_t)(l < 2 ? l : 0) * HD * 32,
                                       cf + (l < 2 ? l : 0) * HD, 1.0f / (float)N);
    }
    int nquads = N * HD / 4;
    int nb1 = (nquads + 255) / 256;
    int nb2 = (G * 192 + 255) / 256;
    k_fin<<<nb1 + nb2, 256, 0, stream>>>(hbuf, ss, praw, gcnt, pool, nquads, G);
}

// Round 5
// 502.722 us; speedup vs baseline: 1.4201x; 1.0924x over previous
//
#include <hip/hip_runtime.h>

#define HD 64
#define BN_EPS 1e-5f

typedef __attribute__((ext_vector_type(8))) short bfrag;
typedef __attribute__((ext_vector_type(4))) float ffrag;

__device__ __forceinline__ unsigned tobf(float x) {
    unsigned u = __float_as_uint(x);
    return (u + 0x7fffu + ((u >> 16) & 1u)) >> 16;
}
__device__ __forceinline__ float bf_lo(unsigned u) { return __uint_as_float(u << 16); }
__device__ __forceinline__ float bf_hi(unsigned u) { return __uint_as_float(u & 0xffff0000u); }

// ---------- CSR construction (rows padded to 16: slot0=self, pads->node N) ----------

__global__ void k_deg(const int* __restrict__ dst, int* __restrict__ deg, int E) {
    int e = blockIdx.x * blockDim.x + threadIdx.x;
    if (e < E) atomicAdd(&deg[dst[e]], 1);
}

// inclusive scan of padded degree (256/block) + dinv + hWs zero-row init
__global__ void k_scan1(const int* __restrict__ deg, int* __restrict__ incl,
                        int* __restrict__ bsums, float* __restrict__ dinv,
                        unsigned* __restrict__ hWs, int N) {
    __shared__ int s[256];
    int tid = threadIdx.x;
    int i = blockIdx.x * 256 + tid;
    if (blockIdx.x == 0 && tid < 32) hWs[(size_t)N * 32 + tid] = 0u;  // zero row
    int d = (i < N) ? deg[i] : 0;
    int pd = (i < N) ? ((d + 16) & ~15) : 0;  // roundup(deg+1, 16)
    s[tid] = pd;
    __syncthreads();
    for (int off = 1; off < 256; off <<= 1) {
        int t = (tid >= off) ? s[tid - off] : 0;
        __syncthreads();
        s[tid] += t;
        __syncthreads();
    }
    if (i < N) {
        incl[i] = s[tid];
        dinv[i] = rsqrtf((float)(d + 1));
    }
    if (tid == 255) bsums[blockIdx.x] = s[255];
}

// rowp from incl + per-block prefix of bsums (reduction, no separate scan pass);
// also writes self edge into slot0 and pad slots -> N
__global__ void k_scan3(int* __restrict__ rowp, const int* __restrict__ deg,
                        const int* __restrict__ incl, const int* __restrict__ bsums,
                        int* __restrict__ ed, int N, int nb) {
    __shared__ float red[256];
    int tid = threadIdx.x;
    int b = blockIdx.x;
    float psum = 0.f;
    for (int t = tid; t < b; t += 256) psum += (float)bsums[t];
    red[tid] = psum;
    __syncthreads();
    for (int off = 128; off > 0; off >>= 1) {
        if (tid < off) red[tid] += red[tid + off];
        __syncthreads();
    }
    int bpre = (int)red[0];
    int i = b * 256 + tid;
    if (i < N) {
        int d = deg[i];
        int pd = (d + 16) & ~15;
        int rv = incl[i] - pd + bpre;  // exclusive global offset
        rowp[i] = rv;
        ed[rv] = i;  // self edge in slot 0
        for (int k = d + 1; k < pd; k++) ed[rv + k] = N;  // pads -> zero row
        if (i == N - 1) rowp[N] = rv + pd;
    }
}

// bucket edges into CSR slots (offset by 1 for self) + per-graph counts fused
__global__ void k_fill(const int* __restrict__ src, const int* __restrict__ dst,
                       const int* __restrict__ rowp, int* __restrict__ cur,
                       int* __restrict__ ed, const int* __restrict__ batch,
                       int* __restrict__ cnt, int E, int N, int G) {
    int e = blockIdx.x * blockDim.x + threadIdx.x;
    if (e < G) {
        int g = e;
        int lo = 0, hi = N;
        while (lo < hi) { int mid = (lo + hi) >> 1; if (batch[mid] < g) lo = mid + 1; else hi = mid; }
        int lo2 = lo, hi2 = N;
        while (lo2 < hi2) { int mid = (lo2 + hi2) >> 1; if (batch[mid] < g + 1) lo2 = mid + 1; else hi2 = mid; }
        cnt[g] = lo2 - lo;
    }
    if (e >= E) return;
    int d = dst[e];
    int pos = rowp[d] + 1 + atomicAdd(&cur[d], 1);
    ed[pos] = src[e];
}

// ---------- MFMA gemm: hWs[i][f] = bf16( dinv[i]*(sum_k A[i][k]*W[f][k] + cb[f]) ) ----------
template<int FP32IN>
__global__ __launch_bounds__(256) void k_gemm2(const void* __restrict__ Aptr,
                                               const void* __restrict__ Wptr,
                                               const float* __restrict__ cb,
                                               const float* __restrict__ dinv,
                                               unsigned short* __restrict__ hWs,
                                               int N, int ntiles) {
    int lane = threadIdx.x & 63;
    int m = lane & 15, quad = lane >> 4;
    bfrag wf[4][2];
    if (FP32IN) {
        const float* W = (const float*)Wptr;
#pragma unroll
        for (int ft = 0; ft < 4; ft++)
#pragma unroll
            for (int kf = 0; kf < 2; kf++) {
                const float4* p4 = (const float4*)(W + (ft * 16 + m) * HD + kf * 32 + quad * 8);
                float4 x0 = p4[0], x1 = p4[1];
                union { unsigned u[4]; bfrag b; } r;
                r.u[0] = tobf(x0.x) | (tobf(x0.y) << 16);
                r.u[1] = tobf(x0.z) | (tobf(x0.w) << 16);
                r.u[2] = tobf(x1.x) | (tobf(x1.y) << 16);
                r.u[3] = tobf(x1.z) | (tobf(x1.w) << 16);
                wf[ft][kf] = r.b;
            }
    } else {
        const unsigned short* W = (const unsigned short*)Wptr;
#pragma unroll
        for (int ft = 0; ft < 4; ft++)
#pragma unroll
            for (int kf = 0; kf < 2; kf++)
                wf[ft][kf] = *(const bfrag*)(W + (ft * 16 + m) * HD + kf * 32 + quad * 8);
    }
    float cbv[4];
#pragma unroll
    for (int ft = 0; ft < 4; ft++) cbv[ft] = cb ? cb[ft * 16 + m] : 0.f;

    int wid = (blockIdx.x * blockDim.x + threadIdx.x) >> 6;
    int nw = (gridDim.x * blockDim.x) >> 6;
    for (int tile = wid; tile < ntiles; tile += nw) {
        int arow = min(tile * 16 + m, N - 1);
        bfrag a0, a1;
        if (FP32IN) {
            const float4* p4 = (const float4*)((const float*)Aptr + (size_t)arow * HD + quad * 8);
            float4 x0 = p4[0], x1 = p4[1], y0 = p4[8], y1 = p4[9];
            union { unsigned u[4]; bfrag b; } r0, r1;
            r0.u[0] = tobf(x0.x) | (tobf(x0.y) << 16);
            r0.u[1] = tobf(x0.z) | (tobf(x0.w) << 16);
            r0.u[2] = tobf(x1.x) | (tobf(x1.y) << 16);
            r0.u[3] = tobf(x1.z) | (tobf(x1.w) << 16);
            r1.u[0] = tobf(y0.x) | (tobf(y0.y) << 16);
            r1.u[1] = tobf(y0.z) | (tobf(y0.w) << 16);
            r1.u[2] = tobf(y1.x) | (tobf(y1.y) << 16);
            r1.u[3] = tobf(y1.z) | (tobf(y1.w) << 16);
            a0 = r0.b; a1 = r1.b;
        } else {
            const unsigned short* p = (const unsigned short*)Aptr + (size_t)arow * HD + quad * 8;
            a0 = *(const bfrag*)p;
            a1 = *(const bfrag*)(p + 32);
        }
        ffrag acc[4];
#pragma unroll
        for (int ft = 0; ft < 4; ft++) {
            acc[ft] = (ffrag){0.f, 0.f, 0.f, 0.f};
            acc[ft] = __builtin_amdgcn_mfma_f32_16x16x32_bf16(a0, wf[ft][0], acc[ft], 0, 0, 0);
            acc[ft] = __builtin_amdgcn_mfma_f32_16x16x32_bf16(a1, wf[ft][1], acc[ft], 0, 0, 0);
        }
        int r0n = tile * 16 + quad * 4;
        float dv[4];
#pragma unroll
        for (int r = 0; r < 4; r++) dv[r] = dinv[min(r0n + r, N - 1)];
#pragma unroll
        for (int ft = 0; ft < 4; ft++)
#pragma unroll
            for (int r = 0; r < 4; r++) {
                int nrow = r0n + r;
                if (nrow < N) {
                    float v = (acc[ft][r] + cbv[ft]) * dv[r];
                    hWs[(size_t)nrow * HD + ft * 16 + m] = (unsigned short)tobf(v);
                }
            }
    }
}

// ---------- aggregation: contiguous padded slot range per wave, 64-slot stages,
// 16-slot groups (8 unconditional gathers/half), last block does BN+fold ----------
__global__ __launch_bounds__(256) void k_agg(const int* __restrict__ rowp,
                                             const int* __restrict__ ed,
                                             const float* __restrict__ dinv,
                                             const unsigned* __restrict__ hWs,
                                             const float* __restrict__ bias,
                                             const int* __restrict__ batch,
                                             void* __restrict__ outp, int outBf,
                                             float* __restrict__ stats,
                                             float* __restrict__ praw,
                                             int N, int chunk,
                                             const float* __restrict__ gam,
                                             const float* __restrict__ bet,
                                             float* __restrict__ ss,
                                             const float* __restrict__ Wnext,
                                             unsigned* __restrict__ Wfb,
                                             float* __restrict__ cf,
                                             float invN, int* __restrict__ ticket) {
    int tid = threadIdx.x;
    int lane = tid & 63;
    int hf = lane >> 5;
    int m = lane & 31;
    int wid = blockIdx.x * 4 + (tid >> 6);
    int i0 = wid * chunk, i1 = min(i0 + chunk, N);
    float b0 = bias[2 * m], b1 = bias[2 * m + 1];
    float bs0 = 0.f, bs1 = 0.f, bq0 = 0.f, bq1 = 0.f;
    int curb = -1;
    float p0 = 0.f, p1 = 0.f;
    if (i0 < N) {
        int sbase = rowp[i0];
        int send = rowp[i1];
        int i = i0;
        int rem = (rowp[i0 + 1] - sbase) >> 4;
        float acc0 = 0.f, acc1 = 0.f;
        for (; sbase < send; sbase += 64) {
            int eidx = ed[sbase + lane];
            int ng = min(4, (send - sbase) >> 4);
            for (int g = 0; g < ng; g++) {
                int t0 = (g << 4) + hf;
                unsigned u[8];
#pragma unroll
                for (int jj = 0; jj < 8; jj++) {
                    int s = __shfl(eidx, t0 + 2 * jj);
                    u[jj] = hWs[(size_t)s * 32 + m];
                }
#pragma unroll
                for (int jj = 0; jj < 8; jj++) {
                    acc0 += bf_lo(u[jj]);
                    acc1 += bf_hi(u[jj]);
                }
                if (--rem == 0) {  // node i complete (wave-uniform)
                    float s0 = acc0 + __shfl_xor(acc0, 32);
                    float s1 = acc1 + __shfl_xor(acc1, 32);
                    float di = dinv[i];
                    float h0 = fmaxf(fmaf(di, s0, b0), 0.f);
                    float h1 = fmaxf(fmaf(di, s1, b1), 0.f);
                    int b = batch[i];
                    if (lane < 32) {
                        if (outBf) ((unsigned*)outp)[(size_t)i * 32 + m] = tobf(h0) | (tobf(h1) << 16);
                        else ((float2*)outp)[(size_t)i * 32 + m] = make_float2(h0, h1);
                        bs0 += h0; bs1 += h1;
                        bq0 = fmaf(h0, h0, bq0); bq1 = fmaf(h1, h1, bq1);
                        if (b != curb) {
                            if (curb >= 0) {
                                atomicAdd(&praw[(size_t)curb * HD + 2 * m], p0);
                                atomicAdd(&praw[(size_t)curb * HD + 2 * m + 1], p1);
                            }
                            curb = b; p0 = h0; p1 = h1;
                        } else { p0 += h0; p1 += h1; }
                    }
                    i++;
                    rem = (i < i1) ? ((rowp[i + 1] - rowp[i]) >> 4) : 0x3fffffff;
                    acc0 = 0.f; acc1 = 0.f;
                }
            }
        }
    }
    if (lane < 32 && curb >= 0) {
        atomicAdd(&praw[(size_t)curb * HD + 2 * m], p0);
        atomicAdd(&praw[(size_t)curb * HD + 2 * m + 1], p1);
    }
    __shared__ float r1s[4][HD], r2s[4][HD];
    int wv = tid >> 6;
    if (lane < 32) {
        r1s[wv][2 * m] = bs0; r1s[wv][2 * m + 1] = bs1;
        r2s[wv][2 * m] = bq0; r2s[wv][2 * m + 1] = bq1;
    }
    __syncthreads();
    if (tid < HD) {
        atomicAdd(&stats[tid], r1s[0][tid] + r1s[1][tid] + r1s[2][tid] + r1s[3][tid]);
        atomicAdd(&stats[HD + tid], r2s[0][tid] + r2s[1][tid] + r2s[2][tid] + r2s[3][tid]);
    }
    // ---- last block: BN finalize + fold into next layer's weights ----
    __shared__ int lastFlag;
    __syncthreads();  // drain this block's stats atomics (vmcnt(0) before barrier)
    if (tid == 0) {
        __threadfence();
        lastFlag = (atomicAdd(ticket, 1) == (int)gridDim.x - 1) ? 1 : 0;
    }
    __syncthreads();
    if (lastFlag) {
        __shared__ float lss[128];
        if (tid < HD) {
            float s1v = atomicAdd(&stats[tid], 0.f);       // coherent read
            float s2v = atomicAdd(&stats[HD + tid], 0.f);
            float mean = s1v * invN;
            float var = s2v * invN - mean * mean;
            float sc = gam[tid] * rsqrtf(var + BN_EPS);
            float sh = bet[tid] - mean * sc;
            ss[tid] = sc; ss[64 + tid] = sh;
            lss[tid] = sc; lss[64 + tid] = sh;
        }
        __syncthreads();
        if (Wnext && tid < HD) {
            float c = 0.f;
            for (int q = 0; q < 32; q++) {
                float wa = Wnext[tid * HD + 2 * q];
                float wb = Wnext[tid * HD + 2 * q + 1];
                Wfb[tid * 32 + q] = tobf(wa * lss[2 * q]) | (tobf(wb * lss[2 * q + 1]) << 16);
                c = fmaf(lss[64 + 2 * q], wa, c);
                c = fmaf(lss[64 + 2 * q + 1], wb, c);
            }
            cf[tid] = c;
        }
    }
}

// fused: normalize final h in place (float4) + pool finalize
__global__ __launch_bounds__(256) void k_fin(float* __restrict__ h,
                                             const float* __restrict__ ss_all,
                                             const float* __restrict__ praw,
                                             const int* __restrict__ cnt,
                                             float* __restrict__ pool,
                                             int nquads, int G) {
    int nb1 = (nquads + 255) >> 8;
    if ((int)blockIdx.x < nb1) {
        int idx = blockIdx.x * 256 + threadIdx.x;
        if (idx >= nquads) return;
        const float* ss = ss_all + 2 * 128;
        float4* h4 = (float4*)h;
        float4 v = h4[idx];
        int f0 = (idx * 4) & 63;
        v.x = fmaf(v.x, ss[f0 + 0], ss[64 + f0 + 0]);
        v.y = fmaf(v.y, ss[f0 + 1], ss[64 + f0 + 1]);
        v.z = fmaf(v.z, ss[f0 + 2], ss[64 + f0 + 2]);
        v.w = fmaf(v.w, ss[f0 + 3], ss[64 + f0 + 3]);
        h4[idx] = v;
    } else {
        int idx = (blockIdx.x - nb1) * 256 + threadIdx.x;
        if (idx >= G * 192) return;
        int g = idx / 192;
        int r = idx - g * 192;
        int l = r >> 6;
        int f = r & 63;
        const float* ss = ss_all + l * 128;
        float v = praw[((size_t)l * G + g) * HD + f];
        pool[idx] = fmaf(ss[f], v, (float)cnt[g] * ss[64 + f]);
    }
}

extern "C" void kernel_launch(void* const* d_in, const int* in_sizes, int n_in,
                              void* d_out, int out_size, void* d_ws, size_t ws_size,
                              hipStream_t stream) {
    const int N = in_sizes[0] / HD;             // 100000
    const int E = in_sizes[1] / 2;              // 1000000
    const int G = (out_size - N * HD) / 192;    // 512

    const float* x = (const float*)d_in[0];
    const int* ei = (const int*)d_in[1];
    const int* srcA = ei;
    const int* dstA = ei + E;
    const int* batch = (const int*)d_in[2];
    const float* W[3]    = {(const float*)d_in[3], (const float*)d_in[7],  (const float*)d_in[11]};
    const float* bias[3] = {(const float*)d_in[4], (const float*)d_in[8],  (const float*)d_in[12]};
    const float* gam[3]  = {(const float*)d_in[5], (const float*)d_in[9],  (const float*)d_in[13]};
    const float* bet[3]  = {(const float*)d_in[6], (const float*)d_in[10], (const float*)d_in[14]};

    char* ws = (char*)d_ws;
    size_t off = 0;
    auto alloc = [&](size_t bytes) -> void* {
        void* p = ws + off;
        off = (off + bytes + 255) & ~(size_t)255;
        return p;
    };
    // zero-region (single memset): deg, cur, stats, tickets, praw
    int* deg     = (int*)alloc((size_t)N * 4);
    int* cur     = (int*)alloc((size_t)N * 4);
    float* stats = (float*)alloc(3 * 128 * 4);
    int* tickets = (int*)alloc(3 * 4);
    float* praw  = (float*)alloc((size_t)3 * G * HD * 4);
    size_t zbytes = off;
    float* dinv  = (float*)alloc((size_t)N * 4);
    int* rowp    = (int*)alloc((size_t)(N + 1) * 4);
    int* incl    = (int*)alloc((size_t)N * 4);
    int* bsums   = (int*)alloc(512 * 4);
    int* ed      = (int*)alloc(((size_t)E + 16 * (size_t)N) * 4 + 512);
    unsigned short* hWs  = (unsigned short*)alloc((size_t)(N + 1) * HD * 2);
    unsigned short* hraw = (unsigned short*)alloc((size_t)N * HD * 2);
    float* ss    = (float*)alloc(3 * 128 * 4);
    unsigned* Wfb = (unsigned*)alloc(2 * HD * 32 * 4);
    float* cf    = (float*)alloc(2 * HD * 4);
    int* gcnt    = (int*)alloc((size_t)G * 4);
    (void)ws_size;

    float* pool = (float*)d_out;                      // [G,192]
    float* hbuf = (float*)d_out + (size_t)G * 192;    // [N,64] final h (fp32)

    hipMemsetAsync(deg, 0, zbytes, stream);

    int nb = (N + 255) / 256;
    k_deg<<<(E + 255) / 256, 256, 0, stream>>>(dstA, deg, E);
    k_scan1<<<nb, 256, 0, stream>>>(deg, incl, bsums, dinv, (unsigned*)hWs, N);
    k_scan3<<<nb, 256, 0, stream>>>(rowp, deg, incl, bsums, ed, N, nb);
    k_fill<<<(E + 255) / 256, 256, 0, stream>>>(srcA, dstA, rowp, cur, ed, batch, gcnt, E, N, G);

    const int AGG_BLOCKS = 2048;
    const int NW = AGG_BLOCKS * 4;
    const int chunk = (N + NW - 1) / NW;
    const int ntiles = (N + 15) / 16;

    for (int l = 0; l < 3; l++) {
        if (l == 0)
            k_gemm2<1><<<640, 256, 0, stream>>>(x, W[0], nullptr, dinv, hWs, N, ntiles);
        else
            k_gemm2<0><<<640, 256, 0, stream>>>(hraw, Wfb + (size_t)(l - 1) * HD * 32,
                                                cf + (l - 1) * HD, dinv, hWs, N, ntiles);
        void* outp = (l < 2) ? (void*)hraw : (void*)hbuf;
        k_agg<<<AGG_BLOCKS, 256, 0, stream>>>(rowp, ed, dinv, (const unsigned*)hWs,
                                              bias[l], batch, outp, (l < 2) ? 1 : 0,
                                              stats + l * 128, praw + (size_t)l * G * HD,
                                              N, chunk,
                                              gam[l], bet[l], ss + l * 128,
                                              (l < 2) ? W[l + 1] : nullptr,
                                              Wfb + (size_t)(l < 2 ? l : 0) * HD * 32,
                                              cf + (l < 2 ? l : 0) * HD,
                                              1.0f / (float)N, tickets + l);
    }
    int nquads = N * HD / 4;
    int nb1 = (nquads + 255) / 256;
    int nb2 = (G * 192 + 255) / 256;
    k_fin<<<nb1 + nb2, 256, 0, stream>>>(hbuf, ss, praw, gcnt, pool, nquads, G);
}